// Round 10
// baseline (451.295 us; speedup 1.0000x reference)
//
#include <hip/hip_runtime.h>

#define BATCH 8
#define SEQ   65536
#define CH    64
#define FILT  64
#define DLAT  256

// R9: occupancy/MLP experiment. R7 (passing, 82.5us) has VGPR=64 -> HW can
// hold 8 blocks/CU (32 waves, 100%), but the 1024-block grid supplied only
// 4 blocks/CU (30%). Per-tile period 25.5K cy vs ~2K cy critical path =
// queueing, i.e. delivered-BW limited; R2 showed 3.2 TB/s delivered at 44%
// occupancy vs R7's 2.4 TB/s at 30% -> delivered BW scales with outstanding
// requests. Double the grid: 256 blocks/batch x 4 tiles, 2048 blocks =
// 8 blocks/CU. LDS 8 x 16.9 KB = 135 KB <= 160. launch_bounds(256,8) pins
// VGPR at 64 (compiler already chose 64 under (256,4) -- same body).
// R8's nt/sc1 streaming stores REVERTED: they bypass the dirty zero lines
// left by the harness's output memset -> stale-line eviction corrupted the
// output (absmax 7.2). Plain stores are the correct-and-passing path.
#define BLK_PER_B   256
#define ROWS_PER_BLK 256
#define TILE_ROWS    64
#define TILES        (ROWS_PER_BLK / TILE_ROWS)   // 4
#define AROWS        66                            // 64 + 2 halo rows
#define ACHUNKS     (AROWS * 8)                    // 528 x 16B chunks

// LDS-hazard-only barrier: ds ops drained (lgkmcnt), global stores stay
// in flight. Intra-block sharing is LDS-only (Abuf), so this is sufficient.
#define BAR() do { asm volatile("s_waitcnt lgkmcnt(0)" ::: "memory"); \
                   __builtin_amdgcn_s_barrier(); } while (0)

typedef __bf16 bfrag  __attribute__((ext_vector_type(8)));
typedef float  floatx4 __attribute__((ext_vector_type(4)));

// ------------- prep: s, d, and folded kernel kmod[b][k][f][c] (bf16) -------
// kmod[b][k][f][c] = ker[k][c][f] * s[b][c] * d[b][f]
__global__ __launch_bounds__(256) void prep_kernel(
    const float* __restrict__ ltnt, const float* __restrict__ ker,
    const float* __restrict__ Wd,   const float* __restrict__ bd,
    __bf16* __restrict__ kmod)
{
    int b = blockIdx.x, tid = threadIdx.x;
    __shared__ float red[4][64];
    __shared__ float s_sh[64];
    __shared__ float d_sh[64];
    int f = tid & 63, p = tid >> 6;

    // s = softplus(ltnt @ Wd + bd) + 1
    float sum = 0.f;
    #pragma unroll 8
    for (int j = p * 64; j < p * 64 + 64; ++j)
        sum += ltnt[b * DLAT + j] * Wd[j * FILT + f];
    red[p][f] = sum;
    __syncthreads();
    if (tid < 64) {
        float tot = red[0][tid] + red[1][tid] + red[2][tid] + red[3][tid] + bd[tid];
        float sp = (tot > 20.f) ? tot : log1pf(expf(tot));
        s_sh[tid] = sp + 1.f;
    }
    __syncthreads();

    // d[f] = rsqrt( sum_{k,c} (ker[k,c,f]*s[c])^2 + eps )   (f32, matches ref)
    float s2 = 0.f;
    for (int k = 0; k < 3; ++k)
        #pragma unroll
        for (int c = p * 16; c < p * 16 + 16; ++c) {
            float w = ker[k * 4096 + c * 64 + f];
            float sc = s_sh[c];
            s2 += w * w * sc * sc;
        }
    __syncthreads();
    red[p][f] = s2;
    __syncthreads();
    if (tid < 64) {
        float tot = red[0][tid] + red[1][tid] + red[2][tid] + red[3][tid];
        d_sh[tid] = rsqrtf(tot + 1e-8f);
    }
    __syncthreads();

    // folded kernel, bf16, layout [k][f][c] contiguous in c
    for (int o = tid; o < 3 * 64 * 64; o += 256) {
        int k = o >> 12, ff = (o >> 6) & 63, c = o & 63;
        kmod[b * 12288 + o] = (__bf16)(ker[k * 4096 + c * 64 + ff] * s_sh[c] * d_sh[ff]);
    }
}

// ---------------------------- conv --------------------------------
__device__ __forceinline__ float4 scale4(float4 v, float s) {
    v.x *= s; v.y *= s; v.z *= s; v.w *= s; return v;
}

__device__ __forceinline__ bfrag cvt8(float4 a, float4 b) {
    bfrag r;
    r[0] = (__bf16)a.x; r[1] = (__bf16)a.y; r[2] = (__bf16)a.z; r[3] = (__bf16)a.w;
    r[4] = (__bf16)b.x; r[5] = (__bf16)b.y; r[6] = (__bf16)b.z; r[7] = (__bf16)b.w;
    return r;
}

// issue global loads for one A tile (rows r0-1 .. r0+64) into registers.
// chunk id = i*256+tid: rho = id>>3 (LDS row), c = id&7 (8-channel group).
// OOB (halo beyond batch edge, or id>=ACHUNKS) -> load row 0, scale 0.
__device__ __forceinline__ void stage_load(float4 pre[3][2],
                                           const float* __restrict__ xb,
                                           int r0, int tid) {
    #pragma unroll
    for (int i = 0; i < 3; ++i) {
        int id  = i * 256 + tid;
        int rho = id >> 3, c = id & 7;
        int g   = r0 - 1 + rho;
        bool ok = (id < ACHUNKS) && ((unsigned)g < (unsigned)SEQ);
        const float* p = xb + (size_t)(ok ? g : 0) * CH + c * 8;
        float s = ok ? 1.f : 0.f;
        pre[i][0] = scale4(*(const float4*)p, s);
        pre[i][1] = scale4(*(const float4*)(p + 4), s);
    }
}

// convert staged registers to bf16 and write to swizzled LDS A tile.
// element index = (rho*64 + c*8) ^ ((rho&7)<<3)  -- 16B-chunk XOR swizzle so
// ds_read_b128 at row-stride 128B spreads across bank groups (2-way max).
__device__ __forceinline__ void stage_write(__bf16* __restrict__ A,
                                            float4 pre[3][2], int tid) {
    #pragma unroll
    for (int i = 0; i < 3; ++i) {
        int id = i * 256 + tid;
        if (id < ACHUNKS) {
            int rho = id >> 3, c = id & 7;
            int idx = (rho * 64 + c * 8) ^ ((rho & 7) << 3);
            *(bfrag*)(A + idx) = cvt8(pre[i][0], pre[i][1]);
        }
    }
}

__global__ __launch_bounds__(256, 8) void conv_kernel(
    const float* __restrict__ data, const __bf16* __restrict__ kmod,
    float* __restrict__ out)
{
    __shared__ __bf16 Abuf[2][AROWS * 64];   // 2 x 8448 B, XOR-swizzled bf16

    int tid  = threadIdx.x;
    int b    = blockIdx.x >> 8;              // 256 blocks per batch
    int blk  = blockIdx.x & (BLK_PER_B - 1);
    int wave = tid >> 6, lane = tid & 63;
    int m = lane & 15, q = lane >> 4;
    int wr = wave >> 1, wf = wave & 1;       // row-half (32 rows), filter-half (32 f)

    // B fragments, M-side operand layout: lane(m,q) = filter (wf*32+nt*16+m),
    // channels q*8.. ; 12 frags = 48 VGPRs.
    const __bf16* kb = kmod + b * 12288;
    bfrag Bf[2][3][2];
    #pragma unroll
    for (int nt = 0; nt < 2; ++nt)
        #pragma unroll
        for (int k = 0; k < 3; ++k)
            #pragma unroll
            for (int h = 0; h < 2; ++h)
                Bf[nt][k][h] = *(const bfrag*)(kb +
                    (k * 64 + wf * 32 + nt * 16 + m) * 64 + h * 32 + q * 8);

    const float* xb = data + (size_t)b * SEQ * CH;
    float*       ob = out  + (size_t)b * SEQ * FILT;
    int base = blk * ROWS_PER_BLK;

    float4 pre[3][2];                        // 24 regs staged prefetch
    stage_load(pre, xb, base, tid);

    #pragma unroll 1
    for (int t = 0; t < TILES; ++t) {
        int r0 = base + t * TILE_ROWS;
        __bf16* A = Abuf[t & 1];

        stage_write(A, pre, tid);            // counted vmcnt: loads(t) only
        BAR();                                // A(t) ready; A(t-1) reads done

        if (t + 1 < TILES)                    // issue next tile's loads early
            stage_load(pre, xb, r0 + TILE_ROWS, tid);

        // ---- compute: 2 row-tiles x 2 filter-tiles, swapped operands ----
        // acc[rt][nt] = C[filter][xrow]: lane(m,q) reg r ->
        //   out[row = r0 + wr*32 + rt*16 + m][filt = wf*32 + nt*16 + q*4 + r]
        floatx4 acc[2][2];
        #pragma unroll
        for (int rt = 0; rt < 2; ++rt)
            #pragma unroll
            for (int nt = 0; nt < 2; ++nt)
                acc[rt][nt] = floatx4{0, 0, 0, 0};

        #pragma unroll
        for (int rt = 0; rt < 2; ++rt) {
            #pragma unroll
            for (int k = 0; k < 3; ++k)
                #pragma unroll
                for (int h = 0; h < 2; ++h) {
                    int rho = wr * 32 + rt * 16 + m + k;     // LDS row (r0-1 ..)
                    bfrag a = *(const bfrag*)(A +
                        ((rho * 64 + h * 32 + q * 8) ^ ((rho & 7) << 3)));
                    #pragma unroll
                    for (int nt = 0; nt < 2; ++nt)
                        acc[rt][nt] = __builtin_amdgcn_mfma_f32_16x16x32_bf16(
                            Bf[nt][k][h], a, acc[rt][nt], 0, 0, 0);
                }
        }

        // ---- direct global stores: dwordx4 = 4 consecutive filters ----
        // per instr: 16 rows x 64B contiguous segments -- L2 write-combines.
        #pragma unroll
        for (int rt = 0; rt < 2; ++rt) {
            int row = r0 + wr * 32 + rt * 16 + m;
            #pragma unroll
            for (int nt = 0; nt < 2; ++nt)
                *(floatx4*)(ob + (size_t)row * FILT + wf * 32 + nt * 16 + q * 4)
                    = acc[rt][nt];
        }
        // stores stay outstanding across BAR(); they drain in background and
        // are only implicitly bounded by the counted vmcnt of stage_write.
    }
}

// ---------------------------------------------------------------------------
extern "C" void kernel_launch(void* const* d_in, const int* in_sizes, int n_in,
                              void* d_out, int out_size, void* d_ws, size_t ws_size,
                              hipStream_t stream) {
    const float* data = (const float*)d_in[0];
    const float* ltnt = (const float*)d_in[1];
    const float* ker  = (const float*)d_in[2];
    const float* Wd   = (const float*)d_in[3];
    const float* bd   = (const float*)d_in[4];
    float* out = (float*)d_out;

    __bf16* kmod = (__bf16*)d_ws;     // 8 * 12288 bf16 = 192 KiB

    prep_kernel<<<BATCH, 256, 0, stream>>>(ltnt, ker, Wd, bd, kmod);
    conv_kernel<<<BATCH * BLK_PER_B, 256, 0, stream>>>(data, kmod, out);
}

// Round 11
// 255.594 us; speedup vs baseline: 1.7657x; 1.7657x over previous
//
#include <hip/hip_runtime.h>

#define BATCH 8
#define SEQ   65536
#define CH    64
#define FILT  64
#define DLAT  256

// R11: 8 blocks/CU WITHOUT a register clamp. Chain of evidence:
//  - R7 (passing, 82.5us): VGPR=64 under (256,4), zero spill, but the
//    1024-block grid supplied only 4 blocks/CU -> 30% occupancy.
//  - R10: (256,8) clamp -> VGPR=32 + ~800 MB spill traffic (FETCH 449 MB),
//    282us -- BUT proved occupancy 76% is reachable and the fabric then
//    delivers 3.5 TB/s sustained (vs 2.4 at 30%, 3.2 at 44%): delivered
//    BW scales with resident waves.
//  - VGPR=64 already permits 8 waves/SIMD (occupancy halves at 64/128/256);
//    the clamp was never needed. Fix: R7 body + (256,4) + 2048-block grid.
//    Residency = min(VGPR 8, LDS 160/16.9~9, grid 8) = 8 blocks/CU.
#define BLK_PER_B   256
#define ROWS_PER_BLK 256
#define TILE_ROWS    64
#define TILES        (ROWS_PER_BLK / TILE_ROWS)   // 4
#define AROWS        66                            // 64 + 2 halo rows
#define ACHUNKS     (AROWS * 8)                    // 528 x 16B chunks

// LDS-hazard-only barrier: ds ops drained (lgkmcnt), global stores stay
// in flight. Intra-block sharing is LDS-only (Abuf), so this is sufficient.
#define BAR() do { asm volatile("s_waitcnt lgkmcnt(0)" ::: "memory"); \
                   __builtin_amdgcn_s_barrier(); } while (0)

typedef __bf16 bfrag  __attribute__((ext_vector_type(8)));
typedef float  floatx4 __attribute__((ext_vector_type(4)));

// ------------- prep: s, d, and folded kernel kmod[b][k][f][c] (bf16) -------
// kmod[b][k][f][c] = ker[k][c][f] * s[b][c] * d[b][f]
__global__ __launch_bounds__(256) void prep_kernel(
    const float* __restrict__ ltnt, const float* __restrict__ ker,
    const float* __restrict__ Wd,   const float* __restrict__ bd,
    __bf16* __restrict__ kmod)
{
    int b = blockIdx.x, tid = threadIdx.x;
    __shared__ float red[4][64];
    __shared__ float s_sh[64];
    __shared__ float d_sh[64];
    int f = tid & 63, p = tid >> 6;

    // s = softplus(ltnt @ Wd + bd) + 1
    float sum = 0.f;
    #pragma unroll 8
    for (int j = p * 64; j < p * 64 + 64; ++j)
        sum += ltnt[b * DLAT + j] * Wd[j * FILT + f];
    red[p][f] = sum;
    __syncthreads();
    if (tid < 64) {
        float tot = red[0][tid] + red[1][tid] + red[2][tid] + red[3][tid] + bd[tid];
        float sp = (tot > 20.f) ? tot : log1pf(expf(tot));
        s_sh[tid] = sp + 1.f;
    }
    __syncthreads();

    // d[f] = rsqrt( sum_{k,c} (ker[k,c,f]*s[c])^2 + eps )   (f32, matches ref)
    float s2 = 0.f;
    for (int k = 0; k < 3; ++k)
        #pragma unroll
        for (int c = p * 16; c < p * 16 + 16; ++c) {
            float w = ker[k * 4096 + c * 64 + f];
            float sc = s_sh[c];
            s2 += w * w * sc * sc;
        }
    __syncthreads();
    red[p][f] = s2;
    __syncthreads();
    if (tid < 64) {
        float tot = red[0][tid] + red[1][tid] + red[2][tid] + red[3][tid];
        d_sh[tid] = rsqrtf(tot + 1e-8f);
    }
    __syncthreads();

    // folded kernel, bf16, layout [k][f][c] contiguous in c
    for (int o = tid; o < 3 * 64 * 64; o += 256) {
        int k = o >> 12, ff = (o >> 6) & 63, c = o & 63;
        kmod[b * 12288 + o] = (__bf16)(ker[k * 4096 + c * 64 + ff] * s_sh[c] * d_sh[ff]);
    }
}

// ---------------------------- conv --------------------------------
__device__ __forceinline__ float4 scale4(float4 v, float s) {
    v.x *= s; v.y *= s; v.z *= s; v.w *= s; return v;
}

__device__ __forceinline__ bfrag cvt8(float4 a, float4 b) {
    bfrag r;
    r[0] = (__bf16)a.x; r[1] = (__bf16)a.y; r[2] = (__bf16)a.z; r[3] = (__bf16)a.w;
    r[4] = (__bf16)b.x; r[5] = (__bf16)b.y; r[6] = (__bf16)b.z; r[7] = (__bf16)b.w;
    return r;
}

// issue global loads for one A tile (rows r0-1 .. r0+64) into registers.
// chunk id = i*256+tid: rho = id>>3 (LDS row), c = id&7 (8-channel group).
// OOB (halo beyond batch edge, or id>=ACHUNKS) -> load row 0, scale 0.
__device__ __forceinline__ void stage_load(float4 pre[3][2],
                                           const float* __restrict__ xb,
                                           int r0, int tid) {
    #pragma unroll
    for (int i = 0; i < 3; ++i) {
        int id  = i * 256 + tid;
        int rho = id >> 3, c = id & 7;
        int g   = r0 - 1 + rho;
        bool ok = (id < ACHUNKS) && ((unsigned)g < (unsigned)SEQ);
        const float* p = xb + (size_t)(ok ? g : 0) * CH + c * 8;
        float s = ok ? 1.f : 0.f;
        pre[i][0] = scale4(*(const float4*)p, s);
        pre[i][1] = scale4(*(const float4*)(p + 4), s);
    }
}

// convert staged registers to bf16 and write to swizzled LDS A tile.
// element index = (rho*64 + c*8) ^ ((rho&7)<<3)  -- 16B-chunk XOR swizzle so
// ds_read_b128 at row-stride 128B spreads across bank groups (2-way max).
__device__ __forceinline__ void stage_write(__bf16* __restrict__ A,
                                            float4 pre[3][2], int tid) {
    #pragma unroll
    for (int i = 0; i < 3; ++i) {
        int id = i * 256 + tid;
        if (id < ACHUNKS) {
            int rho = id >> 3, c = id & 7;
            int idx = (rho * 64 + c * 8) ^ ((rho & 7) << 3);
            *(bfrag*)(A + idx) = cvt8(pre[i][0], pre[i][1]);
        }
    }
}

__global__ __launch_bounds__(256, 4) void conv_kernel(
    const float* __restrict__ data, const __bf16* __restrict__ kmod,
    float* __restrict__ out)
{
    __shared__ __bf16 Abuf[2][AROWS * 64];   // 2 x 8448 B, XOR-swizzled bf16

    int tid  = threadIdx.x;
    int b    = blockIdx.x >> 8;              // 256 blocks per batch
    int blk  = blockIdx.x & (BLK_PER_B - 1);
    int wave = tid >> 6, lane = tid & 63;
    int m = lane & 15, q = lane >> 4;
    int wr = wave >> 1, wf = wave & 1;       // row-half (32 rows), filter-half (32 f)

    // B fragments, M-side operand layout: lane(m,q) = filter (wf*32+nt*16+m),
    // channels q*8.. ; 12 frags = 48 VGPRs.
    const __bf16* kb = kmod + b * 12288;
    bfrag Bf[2][3][2];
    #pragma unroll
    for (int nt = 0; nt < 2; ++nt)
        #pragma unroll
        for (int k = 0; k < 3; ++k)
            #pragma unroll
            for (int h = 0; h < 2; ++h)
                Bf[nt][k][h] = *(const bfrag*)(kb +
                    (k * 64 + wf * 32 + nt * 16 + m) * 64 + h * 32 + q * 8);

    const float* xb = data + (size_t)b * SEQ * CH;
    float*       ob = out  + (size_t)b * SEQ * FILT;
    int base = blk * ROWS_PER_BLK;

    float4 pre[3][2];                        // 24 regs staged prefetch
    stage_load(pre, xb, base, tid);

    #pragma unroll 1
    for (int t = 0; t < TILES; ++t) {
        int r0 = base + t * TILE_ROWS;
        __bf16* A = Abuf[t & 1];

        stage_write(A, pre, tid);            // counted vmcnt: loads(t) only
        BAR();                                // A(t) ready; A(t-1) reads done

        if (t + 1 < TILES)                    // issue next tile's loads early
            stage_load(pre, xb, r0 + TILE_ROWS, tid);

        // ---- compute: 2 row-tiles x 2 filter-tiles, swapped operands ----
        // acc[rt][nt] = C[filter][xrow]: lane(m,q) reg r ->
        //   out[row = r0 + wr*32 + rt*16 + m][filt = wf*32 + nt*16 + q*4 + r]
        floatx4 acc[2][2];
        #pragma unroll
        for (int rt = 0; rt < 2; ++rt)
            #pragma unroll
            for (int nt = 0; nt < 2; ++nt)
                acc[rt][nt] = floatx4{0, 0, 0, 0};

        #pragma unroll
        for (int rt = 0; rt < 2; ++rt) {
            #pragma unroll
            for (int k = 0; k < 3; ++k)
                #pragma unroll
                for (int h = 0; h < 2; ++h) {
                    int rho = wr * 32 + rt * 16 + m + k;     // LDS row (r0-1 ..)
                    bfrag a = *(const bfrag*)(A +
                        ((rho * 64 + h * 32 + q * 8) ^ ((rho & 7) << 3)));
                    #pragma unroll
                    for (int nt = 0; nt < 2; ++nt)
                        acc[rt][nt] = __builtin_amdgcn_mfma_f32_16x16x32_bf16(
                            Bf[nt][k][h], a, acc[rt][nt], 0, 0, 0);
                }
        }

        // ---- direct global stores: dwordx4 = 4 consecutive filters ----
        // per instr: 16 rows x 64B contiguous segments -- L2 write-combines.
        #pragma unroll
        for (int rt = 0; rt < 2; ++rt) {
            int row = r0 + wr * 32 + rt * 16 + m;
            #pragma unroll
            for (int nt = 0; nt < 2; ++nt)
                *(floatx4*)(ob + (size_t)row * FILT + wf * 32 + nt * 16 + q * 4)
                    = acc[rt][nt];
        }
        // stores stay outstanding across BAR(); they drain in background and
        // are only implicitly bounded by the counted vmcnt of stage_write.
    }
}

// ---------------------------------------------------------------------------
extern "C" void kernel_launch(void* const* d_in, const int* in_sizes, int n_in,
                              void* d_out, int out_size, void* d_ws, size_t ws_size,
                              hipStream_t stream) {
    const float* data = (const float*)d_in[0];
    const float* ltnt = (const float*)d_in[1];
    const float* ker  = (const float*)d_in[2];
    const float* Wd   = (const float*)d_in[3];
    const float* bd   = (const float*)d_in[4];
    float* out = (float*)d_out;

    __bf16* kmod = (__bf16*)d_ws;     // 8 * 12288 bf16 = 192 KiB

    prep_kernel<<<BATCH, 256, 0, stream>>>(ltnt, ker, Wd, bd, kmod);
    conv_kernel<<<BATCH * BLK_PER_B, 256, 0, stream>>>(data, kmod, out);
}